// Round 6
// baseline (135.095 us; speedup 1.0000x reference)
//
#include <hip/hip_runtime.h>
#include <hip/hip_bf16.h>

// ---------------- problem dims ----------------
constexpr int Bn   = 256;
constexpr int NOA  = 64, NFA = 4;
constexpr int NOB  = 32, NFB = 3;
constexpr int NS   = 7;
constexpr int DIN  = 128, DL = 64, DG = 64, DH = 256;
constexpr int DGE  = 448;
constexpr int DINA = 704;
constexpr int DINB = 640;

typedef short  short8v __attribute__((ext_vector_type(8)));
typedef float  f32x4   __attribute__((ext_vector_type(4)));

__device__ __forceinline__ unsigned short f2bf(float x) {
  union { float f; unsigned int u; } a; a.f = x;
  unsigned int r = a.u + 0x7fff + ((a.u >> 16) & 1);   // RNE
  return (unsigned short)(r >> 16);
}

// ================= mid: hl(MFMA, inline Wl-transpose) + xsum + rg + wtrans =================
struct MidArgs {
  const float *xA, *xB, *WlA, *WlB, *blA, *blB;
  unsigned short *hlA, *hlB;
  const int *omA, *omB;
  const float *WgA, *bgA, *WgB, *bgB;
  float *rA, *rB;
  const float *W1A, *W1B, *W2A, *W2B;
  unsigned short *W1tA, *W1tB, *W1gtA, *W1gtB, *W2tA, *W2tB;
};

// hl = relu(x @ Wl + bl); Wl transposed in-block; 256 rows/block, wave-private staging.
__device__ void hl_body(const float* __restrict__ x, const float* __restrict__ Wl,
                        const float* __restrict__ bl, unsigned short* __restrict__ hl,
                        int m0, unsigned char* smem) {
  auto Asb = reinterpret_cast<unsigned short(*)[72]>(smem);            // [256][72]
  auto Bsb = reinterpret_cast<unsigned short(*)[136]>(smem + 36864);   // [64][136]
  float (*tile)[65] = reinterpret_cast<float(*)[65]>(smem);            // reuse Asb region
  const int t = threadIdx.x, w = t >> 6, lane = t & 63;
  const int lr = lane & 15, lg = lane >> 4;

  // in-block transpose Wl[128][64] f32 -> Bsb[n][k] bf16
#pragma unroll
  for (int i = 0; i < 32; ++i) {
    int idx = t + i * 256;
    tile[idx >> 6][idx & 63] = Wl[idx];
  }
  __syncthreads();
#pragma unroll
  for (int i = 0; i < 32; ++i) {
    int idx = t + i * 256;
    int n = idx >> 7, k = idx & 127;
    Bsb[n][k] = f2bf(tile[k][n]);
  }
  __syncthreads();

  f32x4 acc[4][4] = {};
  for (int k0 = 0; k0 < DIN; k0 += 64) {
    const float* xp = x + (size_t)(m0 + t) * DIN + k0;
#pragma unroll
    for (int j = 0; j < 8; ++j) {
      float4 a = *(const float4*)(xp + j * 8);
      float4 b = *(const float4*)(xp + j * 8 + 4);
      union { short8v v; unsigned short e[8]; } u;
      u.e[0] = f2bf(a.x); u.e[1] = f2bf(a.y); u.e[2] = f2bf(a.z); u.e[3] = f2bf(a.w);
      u.e[4] = f2bf(b.x); u.e[5] = f2bf(b.y); u.e[6] = f2bf(b.z); u.e[7] = f2bf(b.w);
      *reinterpret_cast<short8v*>(&Asb[t][j * 8]) = u.v;
    }
#pragma unroll
    for (int ks = 0; ks < 2; ++ks) {
      short8v af[4], bf[4];
#pragma unroll
      for (int mi = 0; mi < 4; ++mi)
        af[mi] = *reinterpret_cast<const short8v*>(&Asb[w * 64 + mi * 16 + lr][ks * 32 + lg * 8]);
#pragma unroll
      for (int ni = 0; ni < 4; ++ni)
        bf[ni] = *reinterpret_cast<const short8v*>(&Bsb[ni * 16 + lr][k0 + ks * 32 + lg * 8]);
#pragma unroll
      for (int mi = 0; mi < 4; ++mi)
#pragma unroll
        for (int ni = 0; ni < 4; ++ni)
          acc[mi][ni] = __builtin_amdgcn_mfma_f32_16x16x32_bf16(
              af[mi], bf[ni], acc[mi][ni], 0, 0, 0);
    }
  }
#pragma unroll
  for (int mi = 0; mi < 4; ++mi)
#pragma unroll
    for (int ni = 0; ni < 4; ++ni)
#pragma unroll
      for (int reg = 0; reg < 4; ++reg) {
        int row = mi * 16 + lg * 4 + reg;
        int col = ni * 16 + lr;
        float v = fmaxf(acc[mi][ni][reg] + bl[col], 0.f);
        Asb[w * 64 + row][col] = f2bf(v);
      }
  int m = m0 + w * 64 + lane;
#pragma unroll
  for (int j = 0; j < 8; ++j)
    *reinterpret_cast<short8v*>(hl + (size_t)m * DL + j * 8) =
        *reinterpret_cast<const short8v*>(&Asb[w * 64 + lane][j * 8]);
}

// xsum (masked over objects, f32 from L2) + rg, all wave-local. wave f handles field f.
template<int O, int F>
__device__ void xsum_rg_body(const float* __restrict__ x, const int* __restrict__ om,
                             const float* __restrict__ Wg, const float* __restrict__ bg,
                             float* __restrict__ r, int b, unsigned char* smem) {
  float* xsm = reinterpret_cast<float*>(smem + 36864 + 17408);   // [F][128]
  const int t = threadIdx.x, f = t >> 6, lane = t & 63;
  if (f >= F) return;
  unsigned long long bal = __ballot(lane < O && om[(size_t)b * O + lane] != 0);
  float cnt = (float)__popcll(bal);
  float a0 = 0.f, a1 = 0.f;
  const float* xb = x + ((size_t)b * O * F + f) * DIN + lane;
#pragma unroll 8
  for (int o = 0; o < O; ++o) {
    float m = (float)((bal >> o) & 1ull);
    a0 += m * xb[(size_t)o * F * DIN];
    a1 += m * xb[(size_t)o * F * DIN + 64];
  }
  xsm[f * 128 + lane] = a0;
  xsm[f * 128 + lane + 64] = a1;
  asm volatile("s_waitcnt lgkmcnt(0)" ::: "memory");
  float acc = 0.f;
  const float* wp = Wg + lane;
#pragma unroll 8
  for (int i = 0; i < DIN; ++i) acc += xsm[f * 128 + i] * wp[(size_t)i * DG];
  acc += cnt * bg[lane];
  r[((size_t)b * F + f) * DG + lane] = fmaxf(acc, 0.f);
}

// transpose+convert one 64x64 tile: dst[s][nt*64+n][kt*64+k] = bf16(src[s][koff+kt*64+k][nt*64+n])
__device__ void wtrans_tile(const float* __restrict__ src, unsigned short* __restrict__ dst,
                            int N, int DINc, int koff, int Kout,
                            int s, int kt, int nt, unsigned char* smem) {
  float (*tile)[65] = reinterpret_cast<float(*)[65]>(smem);
  const int t = threadIdx.x;
#pragma unroll
  for (int i = 0; i < 16; ++i) {
    int rr = (t >> 6) + i * 4, c = t & 63;
    tile[rr][c] = src[((size_t)s * DINc + koff + kt * 64 + rr) * N + nt * 64 + c];
  }
  __syncthreads();
#pragma unroll
  for (int i = 0; i < 2; ++i) {
    int cidx = t + i * 256;
    int n = cidx >> 3, kc = (cidx & 7) * 8;
    union { short8v v; unsigned short e[8]; } u;
#pragma unroll
    for (int j = 0; j < 8; ++j) u.e[j] = f2bf(tile[kc + j][n]);
    *reinterpret_cast<short8v*>(dst + ((size_t)s * N + nt * 64 + n) * Kout + kt * 64 + kc) = u.v;
  }
}

__global__ __launch_bounds__(256) void mid_kernel(MidArgs a) {
  __shared__ __align__(16) unsigned char smem[56320];
  const int bid = blockIdx.x;
  if (bid < 256) {
    hl_body(a.xA, a.WlA, a.blA, a.hlA, bid * 256, smem);
    xsum_rg_body<NOA, NFA>(a.xA, a.omA, a.WgA, a.bgA, a.rA, bid, smem);
  } else if (bid < 352) {
    hl_body(a.xB, a.WlB, a.blB, a.hlB, (bid - 256) * 256, smem);
  } else if (bid < 608) {
    xsum_rg_body<NOB, NFB>(a.xB, a.omB, a.WgB, a.bgB, a.rB, bid - 352, smem);
  } else {
    int r = bid - 608;
    if (r < 64)       { wtrans_tile(a.W1A, a.W1tA, 256, DINA, 0, 256,
                                    r / 16, (r % 16) >> 2, r & 3, smem); }
    else if (r < 100) { r -= 64;  wtrans_tile(a.W1B, a.W1tB, 256, DINB, 0, 192,
                                    r / 12, (r % 12) >> 2, r & 3, smem); }
    else if (r < 212) { r -= 100; wtrans_tile(a.W1A, a.W1gtA, 256, DINA, NFA * DL, DGE,
                                    r / 28, (r % 28) >> 2, r & 3, smem); }
    else if (r < 296) { r -= 212; wtrans_tile(a.W1B, a.W1gtB, 256, DINB, NFB * DL, DGE,
                                    r / 28, (r % 28) >> 2, r & 3, smem); }
    else if (r < 360) { r -= 296; wtrans_tile(a.W2A, a.W2tA, 256, DH, 0, DH,
                                    r / 16, (r % 16) >> 2, r & 3, smem); }
    else              { r -= 360; wtrans_tile(a.W2B, a.W2tB, 256, DH, 0, DH,
                                    r / 16, (r % 16) >> 2, r & 3, smem); }
  }
}

// ================= gpr: gpart (MFMA) + reward =================
struct GprArgs {
  const float *rA, *rB; const int *gm;
  const unsigned short *W1gtA, *W1gtB;
  const float *b1A, *b1B;
  float *g1A, *g1B;
  const float *rwW1, *rwb1, *rwW2, *rwb2, *rwW3, *rwb3;
  float *outR;
};

__device__ void gpart_body(const GprArgs& a, int bx, int sg, unsigned char* smem) {
  auto Asb = reinterpret_cast<unsigned short(*)[72]>(smem);           // [64][72]
  auto Bsb = reinterpret_cast<unsigned short(*)[72]>(smem + 9216);    // [256][72]
  const int t = threadIdx.x, w = t >> 6, lane = t & 63;
  const int lr = lane & 15, lg = lane >> 4;
  const int m0 = bx * 64;
  const unsigned short* W1gt; const float* b1; float* g1; int S, sl;
  if (sg < NFA) { W1gt = a.W1gtA; b1 = a.b1A; g1 = a.g1A; S = NFA; sl = sg; }
  else          { W1gt = a.W1gtB; b1 = a.b1B; g1 = a.g1B; S = NFB; sl = sg - NFA; }

  f32x4 acc[4][4] = {};
  for (int kt = 0; kt < 7; ++kt) {
    __syncthreads();
    const int f = kt;
    const float* rsrc = (f < NFA) ? (a.rA + (size_t)f * DG) : (a.rB + (size_t)(f - NFA) * DG);
    const int rstride = (f < NFA) ? NFA * DG : NFB * DG;
#pragma unroll
    for (int i = 0; i < 2; ++i) {
      int c = t + i * 256;
      int row = c >> 3, kc = (c & 7) * 8;
      int b = m0 + row;
      float mk = (a.gm[((size_t)b * NS + sg) * NS + f] != 0) ? 1.f : 0.f;
      const float* rp = rsrc + (size_t)b * rstride + kc;
      union { short8v v; unsigned short e[8]; } u;
#pragma unroll
      for (int j = 0; j < 8; ++j) u.e[j] = f2bf(mk * rp[j]);
      *reinterpret_cast<short8v*>(&Asb[row][kc]) = u.v;
    }
#pragma unroll
    for (int i = 0; i < 8; ++i) {
      int c = t + i * 256;
      int n = c >> 3, kc = (c & 7) * 8;
      *reinterpret_cast<short8v*>(&Bsb[n][kc]) = *reinterpret_cast<const short8v*>(
          W1gt + ((size_t)sl * 256 + n) * DGE + kt * 64 + kc);
    }
    __syncthreads();
#pragma unroll
    for (int ks = 0; ks < 2; ++ks) {
      short8v af[4], bf[4];
#pragma unroll
      for (int mi = 0; mi < 4; ++mi)
        af[mi] = *reinterpret_cast<const short8v*>(&Asb[mi * 16 + lr][ks * 32 + lg * 8]);
#pragma unroll
      for (int ni = 0; ni < 4; ++ni)
        bf[ni] = *reinterpret_cast<const short8v*>(&Bsb[w * 64 + ni * 16 + lr][ks * 32 + lg * 8]);
#pragma unroll
      for (int mi = 0; mi < 4; ++mi)
#pragma unroll
        for (int ni = 0; ni < 4; ++ni)
          acc[mi][ni] = __builtin_amdgcn_mfma_f32_16x16x32_bf16(
              af[mi], bf[ni], acc[mi][ni], 0, 0, 0);
    }
  }
#pragma unroll
  for (int mi = 0; mi < 4; ++mi)
#pragma unroll
    for (int reg = 0; reg < 4; ++reg) {
      int b = m0 + mi * 16 + lg * 4 + reg;
#pragma unroll
      for (int ni = 0; ni < 4; ++ni) {
        int col = w * 64 + ni * 16 + lr;
        g1[((size_t)b * S + sl) * DH + col] = acc[mi][ni][reg] + b1[(size_t)sl * DH + col];
      }
    }
}

__device__ void reward_body(const GprArgs& a, int b, unsigned char* smem) {
  float* Gs = reinterpret_cast<float*>(smem);
  float* h1 = Gs + DGE;
  float* red = h1 + DH;
  const int t = threadIdx.x;
  for (int j = t; j < DGE; j += 256)
    Gs[j] = (j < NFA * DG) ? a.rA[((size_t)b * NFA + (j >> 6)) * DG + (j & 63)]
                           : a.rB[((size_t)b * NFB + ((j - NFA * DG) >> 6)) * DG + (j & 63)];
  __syncthreads();
  float acc = a.rwb1[t];
  for (int j = 0; j < DGE; ++j) acc += Gs[j] * a.rwW1[(size_t)j * DH + t];
  h1[t] = (acc >= 0.f) ? acc : 0.01f * acc;
  __syncthreads();
  acc = a.rwb2[t];
  for (int j = 0; j < DH; ++j) acc += h1[j] * a.rwW2[(size_t)j * DH + t];
  acc = (acc >= 0.f) ? acc : 0.01f * acc;
  red[t] = acc * a.rwW3[t];
  __syncthreads();
  for (int off = 128; off > 0; off >>= 1) {
    if (t < off) red[t] += red[t + off];
    __syncthreads();
  }
  if (t == 0) a.outR[b] = red[0] + a.rwb3[0];
}

__global__ __launch_bounds__(256) void gpr_kernel(GprArgs a) {
  __shared__ __align__(16) unsigned char smem[46080];
  const int bid = blockIdx.x;
  if (bid < 28) gpart_body(a, bid & 3, bid >> 2, smem);
  else          reward_body(a, bid - 28, smem);
}

// ================= dec: streaming MFMA (B from L2/registers, no staging) =================
struct DecArgs {
  const unsigned short *hlA, *hlB, *W1tA, *W1tB, *W2tA, *W2tB;
  const int *lmA, *lmB;
  const float *g1A, *g1B, *WpA, *WpB, *b2A, *b2B, *bpA, *bpB;
  float *outA, *outB;
};

template<int NO, int F>
__device__ __forceinline__ void dec_stream(
    int mt, int s, unsigned short* h1s /*[64][264]*/, float* red /*[512]*/,
    const unsigned short* __restrict__ hl, const int* __restrict__ lm,
    const float* __restrict__ g1,
    const unsigned short* __restrict__ W1t, const unsigned short* __restrict__ W2t,
    const float* __restrict__ Wp, const float* __restrict__ b2,
    const float* __restrict__ bp, float* __restrict__ out) {
  constexpr int K1 = F * 64;
  const int t = threadIdx.x, w = t >> 6, lane = t & 63;
  const int lr = lane & 15, lg = lane >> 4;
  const int m0 = mt * 64;
  const int b0 = m0 / NO;

  int mk0[F], mk1[F];
#pragma unroll
  for (int f = 0; f < F; ++f) {
    mk0[f] = lm[((size_t)b0 * F + s) * F + f];
    mk1[f] = (NO == 32) ? lm[((size_t)(b0 + 1) * F + s) * F + f] : mk0[f];
  }
  float g1r[2][4];
#pragma unroll
  for (int ni = 0; ni < 4; ++ni) {
    int col = w * 64 + ni * 16 + lr;
    g1r[0][ni] = g1[((size_t)b0 * F + s) * DH + col];
    g1r[1][ni] = (NO == 32) ? g1[((size_t)(b0 + 1) * F + s) * DH + col] : g1r[0][ni];
  }

  f32x4 acc[4][4] = {};

  // ---- GEMM1: A = hl rows (global), B = W1t cols (global), mask-skip per f ----
  for (int f = 0; f < F; ++f) {
    if ((mk0[f] | mk1[f]) == 0) continue;
    const unsigned short* Ab = hl + (size_t)m0 * K1 + f * 64;
    const unsigned short* Bb = W1t + ((size_t)s * 256 + w * 64) * K1 + f * 64;
#pragma unroll
    for (int ks = 0; ks < 2; ++ks) {
      const int ko = ks * 32 + lg * 8;
      short8v af[4], bf[4];
#pragma unroll
      for (int mi = 0; mi < 4; ++mi) {
        int ok = (NO == 64) ? 1 : ((mi < 2) ? mk0[f] : mk1[f]);
        if (ok) af[mi] = *reinterpret_cast<const short8v*>(Ab + (size_t)(mi * 16 + lr) * K1 + ko);
        else    af[mi] = short8v{0, 0, 0, 0, 0, 0, 0, 0};
      }
#pragma unroll
      for (int ni = 0; ni < 4; ++ni)
        bf[ni] = *reinterpret_cast<const short8v*>(Bb + (size_t)(ni * 16 + lr) * K1 + ko);
#pragma unroll
      for (int mi = 0; mi < 4; ++mi)
#pragma unroll
        for (int ni = 0; ni < 4; ++ni)
          acc[mi][ni] = __builtin_amdgcn_mfma_f32_16x16x32_bf16(
              af[mi], bf[ni], acc[mi][ni], 0, 0, 0);
    }
  }

  // ---- epilogue 1: +g1, lrelu, bf16 -> h1s (padded LDS) ----
#pragma unroll
  for (int mi = 0; mi < 4; ++mi)
#pragma unroll
    for (int reg = 0; reg < 4; ++reg) {
      int row = mi * 16 + lg * 4 + reg;
      int gi = (NO == 32 && row >= 32) ? 1 : 0;
#pragma unroll
      for (int ni = 0; ni < 4; ++ni) {
        int col = w * 64 + ni * 16 + lr;
        float v = acc[mi][ni][reg] + g1r[gi][ni];
        v = (v >= 0.f) ? v : 0.01f * v;
        h1s[row * 264 + col] = f2bf(v);
        acc[mi][ni][reg] = 0.f;
      }
    }
  __syncthreads();

  // ---- GEMM2: A = h1s (LDS), B = W2t (global), no barriers ----
  const unsigned short* B2 = W2t + ((size_t)s * 256 + w * 64) * 256;
  for (int k0 = 0; k0 < DH; k0 += 64) {
#pragma unroll
    for (int ks = 0; ks < 2; ++ks) {
      const int ko = k0 + ks * 32 + lg * 8;
      short8v af[4], bf[4];
#pragma unroll
      for (int mi = 0; mi < 4; ++mi)
        af[mi] = *reinterpret_cast<const short8v*>(h1s + (mi * 16 + lr) * 264 + ko);
#pragma unroll
      for (int ni = 0; ni < 4; ++ni)
        bf[ni] = *reinterpret_cast<const short8v*>(B2 + (size_t)(ni * 16 + lr) * 256 + ko);
#pragma unroll
      for (int mi = 0; mi < 4; ++mi)
#pragma unroll
        for (int ni = 0; ni < 4; ++ni)
          acc[mi][ni] = __builtin_amdgcn_mfma_f32_16x16x32_bf16(
              af[mi], bf[ni], acc[mi][ni], 0, 0, 0);
    }
  }

  // ---- epilogue 2: lrelu(+b2), Wp, reduce, store ----
  float part[4][4][2] = {};
  const float* Wps = Wp + (size_t)s * DH * 2;
  const float* b2s = b2 + (size_t)s * DH;
#pragma unroll
  for (int ni = 0; ni < 4; ++ni) {
    int col = w * 64 + ni * 16 + lr;
    float wp0 = Wps[col * 2 + 0], wp1 = Wps[col * 2 + 1], bb2 = b2s[col];
#pragma unroll
    for (int mi = 0; mi < 4; ++mi)
#pragma unroll
      for (int reg = 0; reg < 4; ++reg) {
        float v = acc[mi][ni][reg] + bb2;
        v = (v >= 0.f) ? v : 0.01f * v;
        part[mi][reg][0] += v * wp0;
        part[mi][reg][1] += v * wp1;
      }
  }
#pragma unroll
  for (int off = 1; off < 16; off <<= 1)
#pragma unroll
    for (int mi = 0; mi < 4; ++mi)
#pragma unroll
      for (int reg = 0; reg < 4; ++reg) {
        part[mi][reg][0] += __shfl_xor(part[mi][reg][0], off, 64);
        part[mi][reg][1] += __shfl_xor(part[mi][reg][1], off, 64);
      }
  if (lr == 0)
#pragma unroll
    for (int mi = 0; mi < 4; ++mi)
#pragma unroll
      for (int reg = 0; reg < 4; ++reg) {
        int row = mi * 16 + lg * 4 + reg;
        red[(w * 64 + row) * 2 + 0] = part[mi][reg][0];
        red[(w * 64 + row) * 2 + 1] = part[mi][reg][1];
      }
  __syncthreads();
  if (t < 128) {
    int row = t >> 1, p = t & 1;
    float sum = red[(0 * 64 + row) * 2 + p] + red[(1 * 64 + row) * 2 + p]
              + red[(2 * 64 + row) * 2 + p] + red[(3 * 64 + row) * 2 + p];
    out[((size_t)(m0 + row) * F + s) * 2 + p] = sum + bp[(size_t)s * 2 + p];
  }
}

__global__ __launch_bounds__(256, 3) void dec_kernel(DecArgs a) {
  __shared__ __align__(16) unsigned short h1s[64 * 264];   // 33,792 B
  __shared__ float red[512];                                // 2 KB
  const int bid = blockIdx.x;
  if (bid < 1024) {
    dec_stream<NOA, NFA>(bid & 255, bid >> 8, h1s, red, a.hlA, a.lmA, a.g1A,
                         a.W1tA, a.W2tA, a.WpA, a.b2A, a.bpA, a.outA);
  } else {
    int r = bid - 1024;
    dec_stream<NOB, NFB>(r & 127, r >> 7, h1s, red, a.hlB, a.lmB, a.g1B,
                         a.W1tB, a.W2tB, a.WpB, a.b2B, a.bpB, a.outB);
  }
}

// ================= launcher =================
extern "C" void kernel_launch(void* const* d_in, const int* in_sizes, int n_in,
                              void* d_out, int out_size, void* d_ws, size_t ws_size,
                              hipStream_t stream) {
  const float* x_A  = (const float*)d_in[0];
  const float* x_B  = (const float*)d_in[1];
  const int*   gm   = (const int*)d_in[2];
  const int*   lmA  = (const int*)d_in[3];
  const int*   lmB  = (const int*)d_in[4];
  const int*   omA  = (const int*)d_in[5];
  const int*   omB  = (const int*)d_in[6];
  const float* Wl_A = (const float*)d_in[7];
  const float* bl_A = (const float*)d_in[8];
  const float* Wg_A = (const float*)d_in[9];
  const float* bg_A = (const float*)d_in[10];
  const float* Wl_B = (const float*)d_in[11];
  const float* bl_B = (const float*)d_in[12];
  const float* Wg_B = (const float*)d_in[13];
  const float* bg_B = (const float*)d_in[14];
  const float* W1_A = (const float*)d_in[15];
  const float* b1_A = (const float*)d_in[16];
  const float* W2_A = (const float*)d_in[17];
  const float* b2_A = (const float*)d_in[18];
  const float* Wp_A = (const float*)d_in[19];
  const float* bp_A = (const float*)d_in[20];
  const float* W1_B = (const float*)d_in[21];
  const float* b1_B = (const float*)d_in[22];
  const float* W2_B = (const float*)d_in[23];
  const float* b2_B = (const float*)d_in[24];
  const float* Wp_B = (const float*)d_in[25];
  const float* bp_B = (const float*)d_in[26];
  const float* rwW1 = (const float*)d_in[27];
  const float* rwb1 = (const float*)d_in[28];
  const float* rwW2 = (const float*)d_in[29];
  const float* rwb2 = (const float*)d_in[30];
  const float* rwW3 = (const float*)d_in[31];
  const float* rwb3 = (const float*)d_in[32];

  // ---- f32 workspace ----
  float* ws   = (float*)d_ws;
  float* rA   = ws;                        //  65536
  float* rB   = rA + 65536;                //  49152
  float* g1A  = rB + 49152;                // 262144
  float* g1B  = g1A + 262144;              // 196608
  // ---- bf16 (ushort) ----
  unsigned short* us    = (unsigned short*)(g1B + 196608);
  unsigned short* hlA   = us;              // 256*64*256
  unsigned short* hlB   = hlA + 4194304;   // 256*32*192
  unsigned short* W1tA  = hlB + 1572864;   // 4*256*256
  unsigned short* W1tB  = W1tA + 262144;   // 3*256*192
  unsigned short* W2tA  = W1tB + 147456;   // 4*256*256
  unsigned short* W2tB  = W2tA + 262144;   // 3*256*256
  unsigned short* W1gtA = W2tB + 196608;   // 4*256*448
  unsigned short* W1gtB = W1gtA + 458752;  // 3*256*448

  float* outA = (float*)d_out;             // (256,64,4,2)
  float* outB = outA + 131072;             // (256,32,3,2)
  float* outR = outA + 180224;             // (256,)

  MidArgs m;
  m.xA = x_A; m.xB = x_B; m.WlA = Wl_A; m.WlB = Wl_B; m.blA = bl_A; m.blB = bl_B;
  m.hlA = hlA; m.hlB = hlB; m.omA = omA; m.omB = omB;
  m.WgA = Wg_A; m.bgA = bg_A; m.WgB = Wg_B; m.bgB = bg_B;
  m.rA = rA; m.rB = rB;
  m.W1A = W1_A; m.W1B = W1_B; m.W2A = W2_A; m.W2B = W2_B;
  m.W1tA = W1tA; m.W1tB = W1tB; m.W1gtA = W1gtA; m.W1gtB = W1gtB;
  m.W2tA = W2tA; m.W2tB = W2tB;

  GprArgs g;
  g.rA = rA; g.rB = rB; g.gm = gm; g.W1gtA = W1gtA; g.W1gtB = W1gtB;
  g.b1A = b1_A; g.b1B = b1_B; g.g1A = g1A; g.g1B = g1B;
  g.rwW1 = rwW1; g.rwb1 = rwb1; g.rwW2 = rwW2; g.rwb2 = rwb2;
  g.rwW3 = rwW3; g.rwb3 = rwb3; g.outR = outR;

  DecArgs d;
  d.hlA = hlA; d.hlB = hlB; d.W1tA = W1tA; d.W1tB = W1tB;
  d.W2tA = W2tA; d.W2tB = W2tB; d.lmA = lmA; d.lmB = lmB;
  d.g1A = g1A; d.g1B = g1B; d.WpA = Wp_A; d.WpB = Wp_B;
  d.b2A = b2_A; d.b2B = b2_B; d.bpA = bp_A; d.bpB = bp_B;
  d.outA = outA; d.outB = outB;

  mid_kernel<<<1016, 256, 0, stream>>>(m);
  gpr_kernel<<<284, 256, 0, stream>>>(g);
  dec_kernel<<<1408, 256, 0, stream>>>(d);
}

// Round 7
// 82.693 us; speedup vs baseline: 1.6337x; 1.6337x over previous
//
#include <hip/hip_runtime.h>
#include <hip/hip_bf16.h>

// ---------------- problem dims ----------------
constexpr int Bn   = 256;
constexpr int NOA  = 64, NFA = 4;
constexpr int NOB  = 32, NFB = 3;
constexpr int NS   = 7;
constexpr int DIN  = 128, DL = 64, DG = 64, DH = 256;
constexpr int DGE  = 448;
constexpr int DINA = 704;
constexpr int DINB = 640;

typedef short  short8v __attribute__((ext_vector_type(8)));
typedef float  f32x4   __attribute__((ext_vector_type(4)));

__device__ __forceinline__ unsigned short f2bf(float x) {
  union { float f; unsigned int u; } a; a.f = x;
  unsigned int r = a.u + 0x7fff + ((a.u >> 16) & 1);   // RNE
  return (unsigned short)(r >> 16);
}

// Fragment layouts (bf16, 8 elems per 16B chunk):
//   A-frag (hl):  addr = (((m6*KB1 + kb)*4 + mi)*64 + lane)*8 + e
//                 m6=row>>6, mi=(row>>4)&3, lr=row&15, kb=k>>5, lg=(k>>3)&3, lane=lg*16+lr
//   B-frag (W):   addr = (((s*KB + kb)*16 + nchunk)*64 + lane)*8 + e
//                 nchunk=n>>4, lr=n&15, kb/lg as above, lane=lg*16+lr
// A wave's fragment load = 64 consecutive 16B chunks = 1KB fully coalesced.

// ================= mid: hl(MFMA->frag) + xsum + rg + wtrans =================
struct MidArgs {
  const float *xA, *xB, *WlA, *WlB, *blA, *blB;
  unsigned short *hlA, *hlB;
  const int *omA, *omB;
  const float *WgA, *bgA, *WgB, *bgB;
  float *rA, *rB;
  const float *W1A, *W1B, *W2A, *W2B;
  unsigned short *W1tA, *W1tB, *W1gtA, *W1gtB, *W2tA, *W2tB;
};

// hl = relu(x @ Wl + bl); output in A-frag layout. 256 m'-rows/block (m' over (b,o,f)).
template<int F>
__device__ void hl_body(const float* __restrict__ x, const float* __restrict__ Wl,
                        const float* __restrict__ bl, unsigned short* __restrict__ hlf,
                        int m0, unsigned char* smem) {
  auto Asb = reinterpret_cast<unsigned short(*)[72]>(smem);            // [256][72]
  auto Bsb = reinterpret_cast<unsigned short(*)[136]>(smem + 36864);   // [64][136]
  float (*tile)[65] = reinterpret_cast<float(*)[65]>(smem);            // reuse Asb region
  const int t = threadIdx.x, w = t >> 6, lane = t & 63;
  const int lr = lane & 15, lg = lane >> 4;
  constexpr int KB1 = 2 * F;

  // in-block transpose Wl[128][64] f32 -> Bsb[n][k] bf16
#pragma unroll
  for (int i = 0; i < 32; ++i) {
    int idx = t + i * 256;
    tile[idx >> 6][idx & 63] = Wl[idx];
  }
  __syncthreads();
#pragma unroll
  for (int i = 0; i < 32; ++i) {
    int idx = t + i * 256;
    int n = idx >> 7, k = idx & 127;
    Bsb[n][k] = f2bf(tile[k][n]);
  }
  __syncthreads();

  f32x4 acc[4][4] = {};
  for (int k0 = 0; k0 < DIN; k0 += 64) {
    const float* xp = x + (size_t)(m0 + t) * DIN + k0;
#pragma unroll
    for (int j = 0; j < 8; ++j) {
      float4 a = *(const float4*)(xp + j * 8);
      float4 b = *(const float4*)(xp + j * 8 + 4);
      union { short8v v; unsigned short e[8]; } u;
      u.e[0] = f2bf(a.x); u.e[1] = f2bf(a.y); u.e[2] = f2bf(a.z); u.e[3] = f2bf(a.w);
      u.e[4] = f2bf(b.x); u.e[5] = f2bf(b.y); u.e[6] = f2bf(b.z); u.e[7] = f2bf(b.w);
      *reinterpret_cast<short8v*>(&Asb[t][j * 8]) = u.v;
    }
#pragma unroll
    for (int ks = 0; ks < 2; ++ks) {
      short8v af[4], bf[4];
#pragma unroll
      for (int mi = 0; mi < 4; ++mi)
        af[mi] = *reinterpret_cast<const short8v*>(&Asb[w * 64 + mi * 16 + lr][ks * 32 + lg * 8]);
#pragma unroll
      for (int ni = 0; ni < 4; ++ni)
        bf[ni] = *reinterpret_cast<const short8v*>(&Bsb[ni * 16 + lr][k0 + ks * 32 + lg * 8]);
#pragma unroll
      for (int mi = 0; mi < 4; ++mi)
#pragma unroll
        for (int ni = 0; ni < 4; ++ni)
          acc[mi][ni] = __builtin_amdgcn_mfma_f32_16x16x32_bf16(
              af[mi], bf[ni], acc[mi][ni], 0, 0, 0);
    }
  }
  // stage wave-local 64x64 output tile in LDS (row-major)
#pragma unroll
  for (int mi = 0; mi < 4; ++mi)
#pragma unroll
    for (int ni = 0; ni < 4; ++ni)
#pragma unroll
      for (int reg = 0; reg < 4; ++reg) {
        int row = mi * 16 + lg * 4 + reg;
        int col = ni * 16 + lr;
        float v = fmaxf(acc[mi][ni][reg] + bl[col], 0.f);
        Asb[w * 64 + row][col] = f2bf(v);
      }
  // write out in A-frag layout: chunk c = (m'_local, dl-slot)
  const int mpb = m0 + w * 64;
#pragma unroll
  for (int j = 0; j < 8; ++j) {
    int c = lane + j * 64;
    int ml = c >> 3, dls = c & 7;
    int mp = mpb + ml;
    int mrow = mp / F, f = mp % F;
    int m6 = mrow >> 6, mi = (mrow >> 4) & 3, lr2 = mrow & 15;
    int kb = 2 * f + (dls >> 2), lg2 = dls & 3;
    size_t dst = ((((size_t)m6 * KB1 + kb) * 4 + mi) * 64 + (lg2 * 16 + lr2)) * 8;
    *reinterpret_cast<short8v*>(hlf + dst) =
        *reinterpret_cast<const short8v*>(&Asb[w * 64 + ml][dls * 8]);
  }
}

// xsum (masked over objects) + rg, wave-local; wave f handles field f.
template<int O, int F>
__device__ void xsum_rg_body(const float* __restrict__ x, const int* __restrict__ om,
                             const float* __restrict__ Wg, const float* __restrict__ bg,
                             float* __restrict__ r, int b, unsigned char* smem) {
  float* xsm = reinterpret_cast<float*>(smem + 36864 + 17408);   // [F][128]
  const int t = threadIdx.x, f = t >> 6, lane = t & 63;
  if (f >= F) return;
  unsigned long long bal = __ballot(lane < O && om[(size_t)b * O + lane] != 0);
  float cnt = (float)__popcll(bal);
  float a0 = 0.f, a1 = 0.f;
  const float* xb = x + ((size_t)b * O * F + f) * DIN + lane;
#pragma unroll 8
  for (int o = 0; o < O; ++o) {
    float m = (float)((bal >> o) & 1ull);
    a0 += m * xb[(size_t)o * F * DIN];
    a1 += m * xb[(size_t)o * F * DIN + 64];
  }
  xsm[f * 128 + lane] = a0;
  xsm[f * 128 + lane + 64] = a1;
  asm volatile("s_waitcnt lgkmcnt(0)" ::: "memory");
  float acc = 0.f;
  const float* wp = Wg + lane;
#pragma unroll 8
  for (int i = 0; i < DIN; ++i) acc += xsm[f * 128 + i] * wp[(size_t)i * DG];
  acc += cnt * bg[lane];
  r[((size_t)b * F + f) * DG + lane] = fmaxf(acc, 0.f);
}

// old row-major transpose (for W1g used by gpart): dst[s][n][k] = bf16(src[s][koff+k][n])
__device__ void wtrans_tile(const float* __restrict__ src, unsigned short* __restrict__ dst,
                            int N, int DINc, int koff, int Kout,
                            int s, int kt, int nt, unsigned char* smem) {
  float (*tile)[65] = reinterpret_cast<float(*)[65]>(smem);
  const int t = threadIdx.x;
#pragma unroll
  for (int i = 0; i < 16; ++i) {
    int rr = (t >> 6) + i * 4, c = t & 63;
    tile[rr][c] = src[((size_t)s * DINc + koff + kt * 64 + rr) * N + nt * 64 + c];
  }
  __syncthreads();
#pragma unroll
  for (int i = 0; i < 2; ++i) {
    int cidx = t + i * 256;
    int n = cidx >> 3, kc = (cidx & 7) * 8;
    union { short8v v; unsigned short e[8]; } u;
#pragma unroll
    for (int j = 0; j < 8; ++j) u.e[j] = f2bf(tile[kc + j][n]);
    *reinterpret_cast<short8v*>(dst + ((size_t)s * N + nt * 64 + n) * Kout + kt * 64 + kc) = u.v;
  }
}

// B-frag transpose: dst frag addr = (((s*KB + kb)*16 + nchunk)*64 + lane)*8
__device__ void wtrans_frag(const float* __restrict__ src, unsigned short* __restrict__ dst,
                            int DINc, int koff, int KB,
                            int s, int kt, int nt, unsigned char* smem) {
  float (*tile)[65] = reinterpret_cast<float(*)[65]>(smem);
  const int t = threadIdx.x;
#pragma unroll
  for (int i = 0; i < 16; ++i) {
    int rr = (t >> 6) + i * 4, c = t & 63;
    tile[rr][c] = src[((size_t)s * DINc + koff + kt * 64 + rr) * 256 + nt * 64 + c];
  }
  __syncthreads();
#pragma unroll
  for (int i = 0; i < 2; ++i) {
    int cidx = t + i * 256;
    int nl = cidx >> 3, kslot = cidx & 7;
    union { short8v v; unsigned short e[8]; } u;
#pragma unroll
    for (int j = 0; j < 8; ++j) u.e[j] = f2bf(tile[kslot * 8 + j][nl]);
    int kb = kt * 2 + (kslot >> 2);
    int lane = (kslot & 3) * 16 + (nl & 15);
    int nchunk = nt * 4 + (nl >> 4);
    *reinterpret_cast<short8v*>(
        dst + ((((size_t)s * KB + kb) * 16 + nchunk) * 64 + lane) * 8) = u.v;
  }
}

__global__ __launch_bounds__(256) void mid_kernel(MidArgs a) {
  __shared__ __align__(16) unsigned char smem[56320];
  const int bid = blockIdx.x;
  if (bid < 256) {
    hl_body<NFA>(a.xA, a.WlA, a.blA, a.hlA, bid * 256, smem);
    xsum_rg_body<NOA, NFA>(a.xA, a.omA, a.WgA, a.bgA, a.rA, bid, smem);
  } else if (bid < 352) {
    hl_body<NFB>(a.xB, a.WlB, a.blB, a.hlB, (bid - 256) * 256, smem);
  } else if (bid < 608) {
    xsum_rg_body<NOB, NFB>(a.xB, a.omB, a.WgB, a.bgB, a.rB, bid - 352, smem);
  } else {
    int r = bid - 608;
    if (r < 64)       { wtrans_frag(a.W1A, a.W1tA, DINA, 0, 8,
                                    r / 16, (r % 16) >> 2, r & 3, smem); }
    else if (r < 100) { r -= 64;  wtrans_frag(a.W1B, a.W1tB, DINB, 0, 6,
                                    r / 12, (r % 12) >> 2, r & 3, smem); }
    else if (r < 212) { r -= 100; wtrans_tile(a.W1A, a.W1gtA, 256, DINA, NFA * DL, DGE,
                                    r / 28, (r % 28) >> 2, r & 3, smem); }
    else if (r < 296) { r -= 212; wtrans_tile(a.W1B, a.W1gtB, 256, DINB, NFB * DL, DGE,
                                    r / 28, (r % 28) >> 2, r & 3, smem); }
    else if (r < 360) { r -= 296; wtrans_frag(a.W2A, a.W2tA, DH, 0, 8,
                                    r / 16, (r % 16) >> 2, r & 3, smem); }
    else              { r -= 360; wtrans_frag(a.W2B, a.W2tB, DH, 0, 8,
                                    r / 16, (r % 16) >> 2, r & 3, smem); }
  }
}

// ================= gpr: gpart (MFMA) + reward =================
struct GprArgs {
  const float *rA, *rB; const int *gm;
  const unsigned short *W1gtA, *W1gtB;
  const float *b1A, *b1B;
  float *g1A, *g1B;
  const float *rwW1, *rwb1, *rwW2, *rwb2, *rwW3, *rwb3;
  float *outR;
};

__device__ void gpart_body(const GprArgs& a, int bx, int sg, unsigned char* smem) {
  auto Asb = reinterpret_cast<unsigned short(*)[72]>(smem);           // [64][72]
  auto Bsb = reinterpret_cast<unsigned short(*)[72]>(smem + 9216);    // [256][72]
  const int t = threadIdx.x, w = t >> 6, lane = t & 63;
  const int lr = lane & 15, lg = lane >> 4;
  const int m0 = bx * 64;
  const unsigned short* W1gt; const float* b1; float* g1; int S, sl;
  if (sg < NFA) { W1gt = a.W1gtA; b1 = a.b1A; g1 = a.g1A; S = NFA; sl = sg; }
  else          { W1gt = a.W1gtB; b1 = a.b1B; g1 = a.g1B; S = NFB; sl = sg - NFA; }

  f32x4 acc[4][4] = {};
  for (int kt = 0; kt < 7; ++kt) {
    __syncthreads();
    const int f = kt;
    const float* rsrc = (f < NFA) ? (a.rA + (size_t)f * DG) : (a.rB + (size_t)(f - NFA) * DG);
    const int rstride = (f < NFA) ? NFA * DG : NFB * DG;
#pragma unroll
    for (int i = 0; i < 2; ++i) {
      int c = t + i * 256;
      int row = c >> 3, kc = (c & 7) * 8;
      int b = m0 + row;
      float mk = (a.gm[((size_t)b * NS + sg) * NS + f] != 0) ? 1.f : 0.f;
      const float* rp = rsrc + (size_t)b * rstride + kc;
      union { short8v v; unsigned short e[8]; } u;
#pragma unroll
      for (int j = 0; j < 8; ++j) u.e[j] = f2bf(mk * rp[j]);
      *reinterpret_cast<short8v*>(&Asb[row][kc]) = u.v;
    }
#pragma unroll
    for (int i = 0; i < 8; ++i) {
      int c = t + i * 256;
      int n = c >> 3, kc = (c & 7) * 8;
      *reinterpret_cast<short8v*>(&Bsb[n][kc]) = *reinterpret_cast<const short8v*>(
          W1gt + ((size_t)sl * 256 + n) * DGE + kt * 64 + kc);
    }
    __syncthreads();
#pragma unroll
    for (int ks = 0; ks < 2; ++ks) {
      short8v af[4], bf[4];
#pragma unroll
      for (int mi = 0; mi < 4; ++mi)
        af[mi] = *reinterpret_cast<const short8v*>(&Asb[mi * 16 + lr][ks * 32 + lg * 8]);
#pragma unroll
      for (int ni = 0; ni < 4; ++ni)
        bf[ni] = *reinterpret_cast<const short8v*>(&Bsb[w * 64 + ni * 16 + lr][ks * 32 + lg * 8]);
#pragma unroll
      for (int mi = 0; mi < 4; ++mi)
#pragma unroll
        for (int ni = 0; ni < 4; ++ni)
          acc[mi][ni] = __builtin_amdgcn_mfma_f32_16x16x32_bf16(
              af[mi], bf[ni], acc[mi][ni], 0, 0, 0);
    }
  }
#pragma unroll
  for (int mi = 0; mi < 4; ++mi)
#pragma unroll
    for (int reg = 0; reg < 4; ++reg) {
      int b = m0 + mi * 16 + lg * 4 + reg;
#pragma unroll
      for (int ni = 0; ni < 4; ++ni) {
        int col = w * 64 + ni * 16 + lr;
        g1[((size_t)b * S + sl) * DH + col] = acc[mi][ni][reg] + b1[(size_t)sl * DH + col];
      }
    }
}

__device__ void reward_body(const GprArgs& a, int b, unsigned char* smem) {
  float* Gs = reinterpret_cast<float*>(smem);
  float* h1 = Gs + DGE;
  float* red = h1 + DH;
  const int t = threadIdx.x;
  for (int j = t; j < DGE; j += 256)
    Gs[j] = (j < NFA * DG) ? a.rA[((size_t)b * NFA + (j >> 6)) * DG + (j & 63)]
                           : a.rB[((size_t)b * NFB + ((j - NFA * DG) >> 6)) * DG + (j & 63)];
  __syncthreads();
  float acc = a.rwb1[t];
  for (int j = 0; j < DGE; ++j) acc += Gs[j] * a.rwW1[(size_t)j * DH + t];
  h1[t] = (acc >= 0.f) ? acc : 0.01f * acc;
  __syncthreads();
  acc = a.rwb2[t];
  for (int j = 0; j < DH; ++j) acc += h1[j] * a.rwW2[(size_t)j * DH + t];
  acc = (acc >= 0.f) ? acc : 0.01f * acc;
  red[t] = acc * a.rwW3[t];
  __syncthreads();
  for (int off = 128; off > 0; off >>= 1) {
    if (t < off) red[t] += red[t + off];
    __syncthreads();
  }
  if (t == 0) a.outR[b] = red[0] + a.rwb3[0];
}

__global__ __launch_bounds__(256) void gpr_kernel(GprArgs a) {
  __shared__ __align__(16) unsigned char smem[46080];
  const int bid = blockIdx.x;
  if (bid < 28) gpart_body(a, bid & 3, bid >> 2, smem);
  else          reward_body(a, bid - 28, smem);
}

// ================= dec: coalesced fragment streaming, 128x256 tile, 8 waves =================
struct DecArgs {
  const unsigned short *hlA, *hlB, *W1tA, *W1tB, *W2tA, *W2tB;
  const int *lmA, *lmB;
  const float *g1A, *g1B, *WpA, *WpB, *b2A, *b2B, *bpA, *bpB;
  float *outA, *outB;
};

template<int NO, int F>
__device__ __forceinline__ void dec_body(
    int mt, int s, unsigned short* h1s /*[128*264]*/, float* red /*[1024]*/,
    const unsigned short* __restrict__ hlf, const int* __restrict__ lm,
    const float* __restrict__ g1,
    const unsigned short* __restrict__ W1f, const unsigned short* __restrict__ W2f,
    const float* __restrict__ Wp, const float* __restrict__ b2,
    const float* __restrict__ bp, float* __restrict__ out) {
  constexpr int KB1 = 2 * F;
  const int t = threadIdx.x, w = t >> 6, lane = t & 63;
  const int lr = lane & 15, lg = lane >> 4;
  const int mh = w >> 2, nq = w & 3;
  const int m6 = mt * 2 + mh;             // this wave's 64-row block
  const int m0 = mt * 128;

  // masks and g1 (per-wave)
  int mk0[F], mk1[F];
#pragma unroll
  for (int f = 0; f < F; ++f) {
    if (NO == 64) {
      mk0[f] = mk1[f] = lm[((size_t)m6 * F + s) * F + f];
    } else {
      int b0 = m6 * 2;
      mk0[f] = lm[((size_t)b0 * F + s) * F + f];
      mk1[f] = lm[((size_t)(b0 + 1) * F + s) * F + f];
    }
  }
  float g1r[2][4];
#pragma unroll
  for (int ni = 0; ni < 4; ++ni) {
    int col = nq * 64 + ni * 16 + lr;
    if (NO == 64) {
      g1r[0][ni] = g1[((size_t)m6 * F + s) * DH + col];
      g1r[1][ni] = g1r[0][ni];
    } else {
      g1r[0][ni] = g1[((size_t)(m6 * 2) * F + s) * DH + col];
      g1r[1][ni] = g1[((size_t)(m6 * 2 + 1) * F + s) * DH + col];
    }
  }

  f32x4 acc[4][4] = {};

  // ---- GEMM1: fully-coalesced fragment streaming, wave-local mask skip, no barriers ----
  const unsigned short* Afb = hlf + (size_t)m6 * KB1 * 2048;
  const unsigned short* B1b = W1f + (size_t)s * KB1 * 8192 + (size_t)nq * 4 * 512;
#pragma unroll
  for (int f = 0; f < F; ++f) {
    if ((mk0[f] | mk1[f]) == 0) continue;
#pragma unroll
    for (int sub = 0; sub < 2; ++sub) {
      int kb = 2 * f + sub;
      short8v af[4], bf[4];
      const unsigned short* ab = Afb + (size_t)kb * 2048 + lane * 8;
#pragma unroll
      for (int mi = 0; mi < 4; ++mi)
        af[mi] = *reinterpret_cast<const short8v*>(ab + mi * 512);
      if (NO == 32) {
#pragma unroll
        for (int mi = 0; mi < 4; ++mi)
          if (!((mi < 2) ? mk0[f] : mk1[f])) af[mi] = short8v{0,0,0,0,0,0,0,0};
      }
      const unsigned short* bb = B1b + (size_t)kb * 8192 + lane * 8;
#pragma unroll
      for (int ni = 0; ni < 4; ++ni)
        bf[ni] = *reinterpret_cast<const short8v*>(bb + ni * 512);
#pragma unroll
      for (int mi = 0; mi < 4; ++mi)
#pragma unroll
        for (int ni = 0; ni < 4; ++ni)
          acc[mi][ni] = __builtin_amdgcn_mfma_f32_16x16x32_bf16(
              af[mi], bf[ni], acc[mi][ni], 0, 0, 0);
    }
  }

  // ---- epilogue 1: +g1, lrelu, bf16 -> h1s ----
#pragma unroll
  for (int mi = 0; mi < 4; ++mi)
#pragma unroll
    for (int reg = 0; reg < 4; ++reg) {
      int row = mh * 64 + mi * 16 + lg * 4 + reg;
      int gi = (NO == 32) ? (mi >> 1) : 0;
#pragma unroll
      for (int ni = 0; ni < 4; ++ni) {
        int col = nq * 64 + ni * 16 + lr;
        float v = acc[mi][ni][reg] + g1r[gi][ni];
        v = (v >= 0.f) ? v : 0.01f * v;
        h1s[row * 264 + col] = f2bf(v);
        acc[mi][ni][reg] = 0.f;
      }
    }
  __syncthreads();

  // ---- GEMM2: A from LDS, B(W2-frag) streamed coalesced, no barriers ----
  const unsigned short* B2b = W2f + (size_t)s * 8 * 8192 + (size_t)nq * 4 * 512 + lane * 8;
#pragma unroll
  for (int kb = 0; kb < 8; ++kb) {
    short8v af[4], bf[4];
#pragma unroll
    for (int mi = 0; mi < 4; ++mi)
      af[mi] = *reinterpret_cast<const short8v*>(
          h1s + (mh * 64 + mi * 16 + lr) * 264 + kb * 32 + lg * 8);
#pragma unroll
    for (int ni = 0; ni < 4; ++ni)
      bf[ni] = *reinterpret_cast<const short8v*>(B2b + (size_t)kb * 8192 + ni * 512);
#pragma unroll
    for (int mi = 0; mi < 4; ++mi)
#pragma unroll
      for (int ni = 0; ni < 4; ++ni)
        acc[mi][ni] = __builtin_amdgcn_mfma_f32_16x16x32_bf16(
            af[mi], bf[ni], acc[mi][ni], 0, 0, 0);
  }

  // ---- epilogue 2: lrelu(+b2), Wp, reduce, store ----
  float part[4][4][2] = {};
  const float* Wps = Wp + (size_t)s * DH * 2;
  const float* b2s = b2 + (size_t)s * DH;
#pragma unroll
  for (int ni = 0; ni < 4; ++ni) {
    int col = nq * 64 + ni * 16 + lr;
    float wp0 = Wps[col * 2 + 0], wp1 = Wps[col * 2 + 1], bb2 = b2s[col];
#pragma unroll
    for (int mi = 0; mi < 4; ++mi)
#pragma unroll
      for (int reg = 0; reg < 4; ++reg) {
        float v = acc[mi][ni][reg] + bb2;
        v = (v >= 0.f) ? v : 0.01f * v;
        part[mi][reg][0] += v * wp0;
        part[mi][reg][1] += v * wp1;
      }
  }
#pragma unroll
  for (int off = 1; off < 16; off <<= 1)
#pragma unroll
    for (int mi = 0; mi < 4; ++mi)
#pragma unroll
      for (int reg = 0; reg < 4; ++reg) {
        part[mi][reg][0] += __shfl_xor(part[mi][reg][0], off, 64);
        part[mi][reg][1] += __shfl_xor(part[mi][reg][1], off, 64);
      }
  if (lr == 0)
#pragma unroll
    for (int mi = 0; mi < 4; ++mi)
#pragma unroll
      for (int reg = 0; reg < 4; ++reg) {
        int rowin = mi * 16 + lg * 4 + reg;
        red[(w * 64 + rowin) * 2 + 0] = part[mi][reg][0];
        red[(w * 64 + rowin) * 2 + 1] = part[mi][reg][1];
      }
  __syncthreads();
  if (t < 256) {
    int row = t >> 1, p = t & 1;
    int mhr = row >> 6, rowin = row & 63;
    float sum = 0.f;
#pragma unroll
    for (int q = 0; q < 4; ++q)
      sum += red[((mhr * 4 + q) * 64 + rowin) * 2 + p];
    out[((size_t)(m0 + row) * F + s) * 2 + p] = sum + bp[(size_t)s * 2 + p];
  }
}

__global__ __launch_bounds__(512, 4) void dec_kernel(DecArgs a) {
  __shared__ __align__(16) unsigned short h1s[128 * 264];   // 67,584 B
  __shared__ float red[1024];                                // 4 KB
  const int bid = blockIdx.x;
  if (bid < 512) {
    dec_body<NOA, NFA>(bid & 127, bid >> 7, h1s, red, a.hlA, a.lmA, a.g1A,
                       a.W1tA, a.W2tA, a.WpA, a.b2A, a.bpA, a.outA);
  } else {
    int r = bid - 512;
    dec_body<NOB, NFB>(r & 63, r >> 6, h1s, red, a.hlB, a.lmB, a.g1B,
                       a.W1tB, a.W2tB, a.WpB, a.b2B, a.bpB, a.outB);
  }
}

// ================= launcher =================
extern "C" void kernel_launch(void* const* d_in, const int* in_sizes, int n_in,
                              void* d_out, int out_size, void* d_ws, size_t ws_size,
                              hipStream_t stream) {
  const float* x_A  = (const float*)d_in[0];
  const float* x_B  = (const float*)d_in[1];
  const int*   gm   = (const int*)d_in[2];
  const int*   lmA  = (const int*)d_in[3];
  const int*   lmB  = (const int*)d_in[4];
  const int*   omA  = (const int*)d_in[5];
  const int*   omB  = (const int*)d_in[6];
  const float* Wl_A = (const float*)d_in[7];
  const float* bl_A = (const float*)d_in[8];
  const float* Wg_A = (const float*)d_in[9];
  const float* bg_A = (const float*)d_in[10];
  const float* Wl_B = (const float*)d_in[11];
  const float* bl_B = (const float*)d_in[12];
  const float* Wg_B = (const float*)d_in[13];
  const float* bg_B = (const float*)d_in[14];
  const float* W1_A = (const float*)d_in[15];
  const float* b1_A = (const float*)d_in[16];
  const float* W2_A = (const float*)d_in[17];
  const float* b2_A = (const float*)d_in[18];
  const float* Wp_A = (const float*)d_in[19];
  const float* bp_A = (const float*)d_in[20];
  const float* W1_B = (const float*)d_in[21];
  const float* b1_B = (const float*)d_in[22];
  const float* W2_B = (const float*)d_in[23];
  const float* b2_B = (const float*)d_in[24];
  const float* Wp_B = (const float*)d_in[25];
  const float* bp_B = (const float*)d_in[26];
  const float* rwW1 = (const float*)d_in[27];
  const float* rwb1 = (const float*)d_in[28];
  const float* rwW2 = (const float*)d_in[29];
  const float* rwb2 = (const float*)d_in[30];
  const float* rwW3 = (const float*)d_in[31];
  const float* rwb3 = (const float*)d_in[32];

  // ---- f32 workspace ----
  float* ws   = (float*)d_ws;
  float* rA   = ws;                        //  65536
  float* rB   = rA + 65536;                //  49152
  float* g1A  = rB + 49152;                // 262144
  float* g1B  = g1A + 262144;              // 196608
  // ---- bf16 (ushort), all fragment-layout except W1gt ----
  unsigned short* us    = (unsigned short*)(g1B + 196608);
  unsigned short* hlA   = us;              // 256*8*4*64*8   = 4,194,304
  unsigned short* hlB   = hlA + 4194304;   // 128*6*4*64*8   = 1,572,864
  unsigned short* W1tA  = hlB + 1572864;   // 4*8*16*64*8    =   262,144
  unsigned short* W1tB  = W1tA + 262144;   // 3*6*16*64*8    =   147,456
  unsigned short* W2tA  = W1tB + 147456;   // 4*8*16*64*8    =   262,144
  unsigned short* W2tB  = W2tA + 262144;   // 3*8*16*64*8    =   196,608
  unsigned short* W1gtA = W2tB + 196608;   // 4*256*448 (row-major)
  unsigned short* W1gtB = W1gtA + 458752;  // 3*256*448 (row-major)

  float* outA = (float*)d_out;             // (256,64,4,2)
  float* outB = outA + 131072;             // (256,32,3,2)
  float* outR = outA + 180224;             // (256,)

  MidArgs m;
  m.xA = x_A; m.xB = x_B; m.WlA = Wl_A; m.WlB = Wl_B; m.blA = bl_A; m.blB = bl_B;
  m.hlA = hlA; m.hlB = hlB; m.omA = omA; m.omB = omB;
  m.WgA = Wg_A; m.bgA = bg_A; m.WgB = Wg_B; m.bgB = bg_B;
  m.rA = rA; m.rB = rB;
  m.W1A = W1_A; m.W1B = W1_B; m.W2A = W2_A; m.W2B = W2_B;
  m.W1tA = W1tA; m.W1tB = W1tB; m.W1gtA = W1gtA; m.W1gtB = W1gtB;
  m.W2tA = W2tA; m.W2tB = W2tB;

  GprArgs g;
  g.rA = rA; g.rB = rB; g.gm = gm; g.W1gtA = W1gtA; g.W1gtB = W1gtB;
  g.b1A = b1_A; g.b1B = b1_B; g.g1A = g1A; g.g1B = g1B;
  g.rwW1 = rwW1; g.rwb1 = rwb1; g.rwW2 = rwW2; g.rwb2 = rwb2;
  g.rwW3 = rwW3; g.rwb3 = rwb3; g.outR = outR;

  DecArgs d;
  d.hlA = hlA; d.hlB = hlB; d.W1tA = W1tA; d.W1tB = W1tB;
  d.W2tA = W2tA; d.W2tB = W2tB; d.lmA = lmA; d.lmB = lmB;
  d.g1A = g1A; d.g1B = g1B; d.WpA = Wp_A; d.WpB = Wp_B;
  d.b2A = b2_A; d.b2B = b2_B; d.bpA = bp_A; d.bpB = bp_B;
  d.outA = outA; d.outB = outB;

  mid_kernel<<<1016, 256, 0, stream>>>(m);
  gpr_kernel<<<284, 256, 0, stream>>>(g);
  dec_kernel<<<704, 512, 0, stream>>>(d);
}